// Round 3
// baseline (341.764 us; speedup 1.0000x reference)
//
#include <hip/hip_runtime.h>
#include <stdint.h>

typedef unsigned short ushort_t;
typedef __attribute__((ext_vector_type(4))) unsigned short ushort4_t;
typedef __attribute__((ext_vector_type(8))) short short8;
typedef __attribute__((ext_vector_type(4))) float float4_t;

#define AS1 __attribute__((address_space(1)))
#define AS3 __attribute__((address_space(3)))

__device__ inline ushort_t f2bf(float f) {
    unsigned x = __builtin_bit_cast(unsigned, f);
    unsigned r = x + 0x7fffu + ((x >> 16) & 1u);
    return (ushort_t)(r >> 16);
}

// ---------- transpose+convert: in fp32 [R][C] -> out bf16 [C][R] ----------
__global__ __launch_bounds__(256) void transpose_f32_bf16(const float* __restrict__ in,
                                                          ushort_t* __restrict__ out,
                                                          int R, int C) {
    __shared__ __align__(16) ushort_t tile[64][65];
    int c0 = blockIdx.x * 64, r0 = blockIdx.y * 64;
    int t = threadIdx.x;
    for (int i = 0; i < 16; i++) {
        int idx = t + i * 256;
        int lr = idx >> 6, lc = idx & 63;
        tile[lr][lc] = f2bf(in[(size_t)(r0 + lr) * C + c0 + lc]);
    }
    __syncthreads();
    for (int i = 0; i < 16; i++) {
        int idx = t + i * 256;
        int lr = idx >> 6, lc = idx & 63;
        out[(size_t)(c0 + lr) * R + r0 + lc] = tile[lc][lr];
    }
}

// ---------- GEMM: C[M][N] = A[M][K] @ Bt[N][K]^T, bf16 MFMA ----------
// AFP32=1: A is fp32, convert-staged to LDS.  AFP32=0: A is bf16, global_load_lds.
// EPI=0: scatter bf16 to q/k/v.  EPI=1: add fp32 bias, write fp32 out.
template <int EPI, int AFP32>
__global__ __launch_bounds__(256) void gemm_bt(
    const void* __restrict__ Ap, const ushort_t* __restrict__ Bt,
    int M, int N, int K,
    ushort_t* __restrict__ outQ, ushort_t* __restrict__ outK, ushort_t* __restrict__ outV,
    const float* __restrict__ bias, float* __restrict__ outC) {
    __shared__ __align__(16) ushort_t As[128 * 64];
    __shared__ __align__(16) ushort_t Bs[128 * 64];
    int t = threadIdx.x;
    int w = t >> 6, lane = t & 63;
    int quad = lane >> 4, l15 = lane & 15;
    int wM = w >> 1, wN = w & 1;
    int tM = blockIdx.y * 128, tN = blockIdx.x * 128;

    float4_t acc[4][4];
    for (int i = 0; i < 4; i++)
        for (int j = 0; j < 4; j++) acc[i][j] = (float4_t){0.f, 0.f, 0.f, 0.f};

    int lrow = lane >> 3;          // 0..7
    int lcol8 = (lane & 7) * 8;    // ushort col offset

    const ushort_t* Abf = (const ushort_t*)Ap;
    const float* Afp = (const float*)Ap;
    const ushort_t* Bbase = Bt + (size_t)(tN + w * 32) * K;

    for (int k0 = 0; k0 < K; k0 += 64) {
        __syncthreads();
        if (AFP32) {
            // stage A fp32 -> bf16: 128 rows x 64 k = 2048 float4 loads, 8/thread
            for (int i = 0; i < 8; i++) {
                int e = t + i * 256;
                int row = e >> 4, c4 = (e & 15) * 4;
                const float4_t f = *(const float4_t*)&Afp[(size_t)(tM + row) * K + k0 + c4];
                ushort4_t u;
                u.x = f2bf(f.x); u.y = f2bf(f.y); u.z = f2bf(f.z); u.w = f2bf(f.w);
                *(ushort4_t*)&As[row * 64 + c4] = u;
            }
        } else {
            const ushort_t* Abase = Abf + (size_t)(tM + w * 32) * K;
            for (int i = 0; i < 4; i++) {
                const ushort_t* ga = Abase + (size_t)(i * 8 + lrow) * K + k0 + lcol8;
                __builtin_amdgcn_global_load_lds((AS1 void*)ga, (AS3 void*)&As[(w * 32 + i * 8) * 64], 16, 0, 0);
            }
        }
        for (int i = 0; i < 4; i++) {
            const ushort_t* gb = Bbase + (size_t)(i * 8 + lrow) * K + k0 + lcol8;
            __builtin_amdgcn_global_load_lds((AS1 void*)gb, (AS3 void*)&Bs[(w * 32 + i * 8) * 64], 16, 0, 0);
        }
        __syncthreads();
        for (int kt = 0; kt < 2; kt++) {
            short8 af[4], bf[4];
            for (int m = 0; m < 4; m++)
                af[m] = *(const short8*)&As[(wM * 64 + m * 16 + l15) * 64 + kt * 32 + quad * 8];
            for (int n = 0; n < 4; n++)
                bf[n] = *(const short8*)&Bs[(wN * 64 + n * 16 + l15) * 64 + kt * 32 + quad * 8];
            for (int m = 0; m < 4; m++)
                for (int n = 0; n < 4; n++)
                    acc[m][n] = __builtin_amdgcn_mfma_f32_16x16x32_bf16(af[m], bf[n], acc[m][n], 0, 0, 0);
        }
    }

    if (EPI == 0) {
        // scatter into q[B,H,N,d], k[B,H,N,d], v[B,H,d,N]; gn decides which
        for (int m = 0; m < 4; m++) {
            int gm = tM + wM * 64 + m * 16 + quad * 4;
            for (int n = 0; n < 4; n++) {
                int gn = tN + wN * 64 + n * 16 + l15;
                int three = gn >> 10;
                int h = (gn >> 6) & 15;
                int dd = gn & 63;
                for (int r = 0; r < 4; r++) {
                    int row = gm + r;
                    int b = row >> 11;       // M = 2*2048
                    int ns = row & 2047;
                    ushort_t val = f2bf(acc[m][n][r]);
                    if (three == 0)
                        outQ[(((size_t)(b * 16 + h) * 2048 + ns) << 6) + dd] = val;
                    else if (three == 1)
                        outK[(((size_t)(b * 16 + h) * 2048 + ns) << 6) + dd] = val;
                    else
                        outV[((size_t)(b * 16 + h) * 64 + dd) * 2048 + ns] = val;
                }
            }
        }
    } else {
        for (int m = 0; m < 4; m++) {
            int gm = tM + wM * 64 + m * 16 + quad * 4;
            for (int n = 0; n < 4; n++) {
                int gn = tN + wN * 64 + n * 16 + l15;
                float bv = bias[gn];
                for (int r = 0; r < 4; r++)
                    outC[(size_t)(gm + r) * N + gn] = acc[m][n][r] + bv;
            }
        }
    }
}

// ---------- flash attention ----------
// q,k: [BH][N][d] bf16; vT: [BH][d][N] bf16; out: [B][N][H*d] bf16
__global__ __launch_bounds__(256) void attn_kernel(
    const ushort_t* __restrict__ q, const ushort_t* __restrict__ k,
    const ushort_t* __restrict__ vT, const int* __restrict__ pad,
    const int* __restrict__ csp, ushort_t* __restrict__ out) {
    __shared__ __align__(16) ushort_t Ks[64 * 64];
    __shared__ __align__(16) ushort_t Vs[64 * 64];
    __shared__ __align__(16) ushort_t Ps[4][16 * 64];

    int cs = csp[0];
    int t = threadIdx.x, w = t >> 6, lane = t & 63;
    int quad = lane >> 4, l15 = lane & 15;
    int bh = blockIdx.y;
    int b = bh >> 4, h = bh & 15;
    int q0 = blockIdx.x * 64;
    const float scale = 0.125f;  // d=64

    const ushort_t* qbase = q + ((size_t)bh * 2048 + q0 + w * 16 + l15) * 64;
    short8 qf0 = *(const short8*)(qbase + quad * 8);
    short8 qf1 = *(const short8*)(qbase + 32 + quad * 8);

    float4_t O[4];
    for (int i = 0; i < 4; i++) O[i] = (float4_t){0.f, 0.f, 0.f, 0.f};
    float mrun[4], lrun[4];
    for (int r = 0; r < 4; r++) { mrun[r] = -1e30f; lrun[r] = 0.f; }

    int csT = (cs + 63) >> 6;
    int nT = (int)blockIdx.x + 1;
    if (csT > nT) nT = csT;

    int lrow = lane >> 3;
    int lcol = (lane & 7) * 8;

    const ushort_t* kbase = k + (size_t)bh * 2048 * 64;
    const ushort_t* vbase = vT + (size_t)bh * 64 * 2048;

    for (int it = 0; it < nT; it++) {
        int k0 = it * 64;
        __syncthreads();
        for (int i = 0; i < 2; i++) {
            int row = w * 16 + i * 8 + lrow;
            const ushort_t* gk = kbase + ((size_t)k0 + row) * 64 + lcol;
            __builtin_amdgcn_global_load_lds((AS1 void*)gk, (AS3 void*)&Ks[(w * 16 + i * 8) * 64], 16, 0, 0);
            const ushort_t* gv = vbase + (size_t)row * 2048 + k0 + lcol;
            __builtin_amdgcn_global_load_lds((AS1 void*)gv, (AS3 void*)&Vs[(w * 16 + i * 8) * 64], 16, 0, 0);
        }
        __syncthreads();

        float4_t s[4];
        for (int ks = 0; ks < 4; ks++) {
            float4_t a = (float4_t){0.f, 0.f, 0.f, 0.f};
            short8 kf0 = *(const short8*)&Ks[(ks * 16 + l15) * 64 + quad * 8];
            short8 kf1 = *(const short8*)&Ks[(ks * 16 + l15) * 64 + 32 + quad * 8];
            a = __builtin_amdgcn_mfma_f32_16x16x32_bf16(qf0, kf0, a, 0, 0, 0);
            a = __builtin_amdgcn_mfma_f32_16x16x32_bf16(qf1, kf1, a, 0, 0, 0);
            s[ks] = a;
        }
        int prow = q0 + w * 16 + quad * 4;
        for (int ks = 0; ks < 4; ks++) {
            int key = k0 + ks * 16 + l15;
            bool pm = pad[b * 2048 + key] != 0;
            for (int r = 0; r < 4; r++) {
                int row = prow + r;
                bool ok = (!pm) && ((key <= row) || (key < cs));
                s[ks][r] = ok ? s[ks][r] * scale : -1e30f;
            }
        }
        float p[4][4];
        for (int r = 0; r < 4; r++) {
            float mx = fmaxf(fmaxf(s[0][r], s[1][r]), fmaxf(s[2][r], s[3][r]));
            mx = fmaxf(mx, __shfl_xor(mx, 1, 64));
            mx = fmaxf(mx, __shfl_xor(mx, 2, 64));
            mx = fmaxf(mx, __shfl_xor(mx, 4, 64));
            mx = fmaxf(mx, __shfl_xor(mx, 8, 64));
            float mnew = fmaxf(mrun[r], mx);
            float alpha = __expf(mrun[r] - mnew);
            float rs = 0.f;
            for (int ks = 0; ks < 4; ks++) {
                float pv = (s[ks][r] < -1e29f) ? 0.f : __expf(s[ks][r] - mnew);
                p[ks][r] = pv;
                rs += pv;
            }
            rs += __shfl_xor(rs, 1, 64);
            rs += __shfl_xor(rs, 2, 64);
            rs += __shfl_xor(rs, 4, 64);
            rs += __shfl_xor(rs, 8, 64);
            lrun[r] = lrun[r] * alpha + rs;
            mrun[r] = mnew;
            for (int d = 0; d < 4; d++) O[d][r] *= alpha;
        }
        for (int ks = 0; ks < 4; ks++)
            for (int r = 0; r < 4; r++)
                Ps[w][(quad * 4 + r) * 64 + ks * 16 + l15] = f2bf(p[ks][r]);
        short8 pf0 = *(const short8*)&Ps[w][l15 * 64 + quad * 8];
        short8 pf1 = *(const short8*)&Ps[w][l15 * 64 + 32 + quad * 8];
        for (int d = 0; d < 4; d++) {
            short8 vf0 = *(const short8*)&Vs[(d * 16 + l15) * 64 + quad * 8];
            short8 vf1 = *(const short8*)&Vs[(d * 16 + l15) * 64 + 32 + quad * 8];
            O[d] = __builtin_amdgcn_mfma_f32_16x16x32_bf16(pf0, vf0, O[d], 0, 0, 0);
            O[d] = __builtin_amdgcn_mfma_f32_16x16x32_bf16(pf1, vf1, O[d], 0, 0, 0);
        }
    }

    for (int r = 0; r < 4; r++) {
        float inv = lrun[r] > 0.f ? 1.f / lrun[r] : 0.f;
        int row = q0 + w * 16 + quad * 4 + r;
        size_t ob = ((size_t)b * 2048 + row) * 1024 + h * 64;
        for (int d = 0; d < 4; d++) {
            float fv = O[d][r] * inv;
            if (!(fabsf(fv) < 1e30f)) fv = 0.f;  // NaN/Inf firewall (diagnostic)
            out[ob + d * 16 + l15] = f2bf(fv);
        }
    }
}

extern "C" void kernel_launch(void* const* d_in, const int* in_sizes, int n_in,
                              void* d_out, int out_size, void* d_ws, size_t ws_size,
                              hipStream_t stream) {
    const float* x = (const float*)d_in[0];        // fp32 [2,2048,1024]
    const int* pad = (const int*)d_in[1];          // int32 [2,2048]
    const int* cs = (const int*)d_in[2];           // int32 [1]
    const float* wqkv = (const float*)d_in[3];     // fp32 [1024,3072]
    const float* wproj = (const float*)d_in[4];    // fp32 [1024,1024]
    const float* bproj = (const float*)d_in[5];    // fp32 [1024]
    float* out = (float*)d_out;                    // fp32 [2,2048,1024]

    // ws layout, peak 32 MB via lifetime aliasing (units: ushort):
    //   q[0,4M) k[4M,8M) v[8M,12M)
    //   wqkvT[12M, 12M+3M) -> dies after gemm1; ao[12M,16M) after attn starts
    //   wprojT[0,1M) after q dies
    ushort_t* ws = (ushort_t*)d_ws;
    ushort_t* qws = ws;
    ushort_t* kws = ws + (size_t)4194304;
    ushort_t* vws = ws + (size_t)8388608;
    ushort_t* wqkvT = ws + (size_t)12582912;
    ushort_t* aows = ws + (size_t)12582912;
    ushort_t* wprojT = ws;

    // 1) W_qkv fp32 [1024][3072] -> bf16 [3072][1024]
    transpose_f32_bf16<<<dim3(48, 16), 256, 0, stream>>>(wqkv, wqkvT, 1024, 3072);
    // 2) qkv projection: x fp32 (convert-staged) @ wqkvT bf16 -> q/k/v bf16
    gemm_bt<0, 1><<<dim3(24, 32), 256, 0, stream>>>(x, wqkvT, 4096, 3072, 1024,
                                                    qws, kws, vws, nullptr, nullptr);
    // 3) attention -> ao bf16 (over dead wqkvT)
    attn_kernel<<<dim3(32, 32), 256, 0, stream>>>(qws, kws, vws, pad, cs, aows);
    // 4) W_proj fp32 [1024][1024] -> bf16 T (over dead q)
    transpose_f32_bf16<<<dim3(16, 16), 256, 0, stream>>>(wproj, wprojT, 1024, 1024);
    // 5) output projection + fp32 bias -> fp32 out
    gemm_bt<1, 0><<<dim3(8, 32), 256, 0, stream>>>(aows, wprojT, 4096, 1024, 1024,
                                                   nullptr, nullptr, nullptr, bproj, out);
}

// Round 4
// 251.420 us; speedup vs baseline: 1.3593x; 1.3593x over previous
//
#include <hip/hip_runtime.h>
#include <stdint.h>

typedef unsigned short ushort_t;
typedef __attribute__((ext_vector_type(4))) unsigned short ushort4_t;
typedef __attribute__((ext_vector_type(8))) short short8;
typedef __attribute__((ext_vector_type(4))) float float4_t;

#define AS1 __attribute__((address_space(1)))
#define AS3 __attribute__((address_space(3)))

__device__ inline ushort_t f2bf(float f) {
    unsigned x = __builtin_bit_cast(unsigned, f);
    unsigned r = x + 0x7fffu + ((x >> 16) & 1u);
    return (ushort_t)(r >> 16);
}

// ---------- transpose+convert: in fp32 [R][C] -> out bf16 [C][R] ----------
__global__ __launch_bounds__(256) void transpose_f32_bf16(const float* __restrict__ in,
                                                          ushort_t* __restrict__ out,
                                                          int R, int C) {
    __shared__ __align__(16) ushort_t tile[64][65];
    int c0 = blockIdx.x * 64, r0 = blockIdx.y * 64;
    int t = threadIdx.x;
    for (int i = 0; i < 16; i++) {
        int idx = t + i * 256;
        int lr = idx >> 6, lc = idx & 63;
        tile[lr][lc] = f2bf(in[(size_t)(r0 + lr) * C + c0 + lc]);
    }
    __syncthreads();
    for (int i = 0; i < 16; i++) {
        int idx = t + i * 256;
        int lr = idx >> 6, lc = idx & 63;
        out[(size_t)(c0 + lr) * R + r0 + lc] = tile[lc][lr];
    }
}

// ---------- GEMM: C[M][N] = A[M][K] @ Bt[N][K]^T, bf16 MFMA ----------
// AFP32=1: A fp32 convert-staged.  EPI=0: scatter bf16 to q/k/v (all [b,h,n,d]).
// EPI=1: add fp32 bias, write fp32 out.
template <int EPI, int AFP32>
__global__ __launch_bounds__(256) void gemm_bt(
    const void* __restrict__ Ap, const ushort_t* __restrict__ Bt,
    int M, int N, int K,
    ushort_t* __restrict__ outQ, ushort_t* __restrict__ outK, ushort_t* __restrict__ outV,
    const float* __restrict__ bias, float* __restrict__ outC) {
    __shared__ __align__(16) ushort_t As[128 * 64];
    __shared__ __align__(16) ushort_t Bs[128 * 64];
    int t = threadIdx.x;
    int w = t >> 6, lane = t & 63;
    int quad = lane >> 4, l15 = lane & 15;
    int wM = w >> 1, wN = w & 1;
    int tM = blockIdx.y * 128, tN = blockIdx.x * 128;

    float4_t acc[4][4];
    for (int i = 0; i < 4; i++)
        for (int j = 0; j < 4; j++) acc[i][j] = (float4_t){0.f, 0.f, 0.f, 0.f};

    int lrow = lane >> 3;
    int lcol8 = (lane & 7) * 8;

    const ushort_t* Abf = (const ushort_t*)Ap;
    const float* Afp = (const float*)Ap;
    const ushort_t* Bbase = Bt + (size_t)(tN + w * 32) * K;

    for (int k0 = 0; k0 < K; k0 += 64) {
        __syncthreads();
        if (AFP32) {
            for (int i = 0; i < 8; i++) {
                int e = t + i * 256;
                int row = e >> 4, c4 = (e & 15) * 4;
                const float4_t f = *(const float4_t*)&Afp[(size_t)(tM + row) * K + k0 + c4];
                ushort4_t u;
                u.x = f2bf(f.x); u.y = f2bf(f.y); u.z = f2bf(f.z); u.w = f2bf(f.w);
                *(ushort4_t*)&As[row * 64 + c4] = u;
            }
        } else {
            const ushort_t* Abase = Abf + (size_t)(tM + w * 32) * K;
            for (int i = 0; i < 4; i++) {
                const ushort_t* ga = Abase + (size_t)(i * 8 + lrow) * K + k0 + lcol8;
                __builtin_amdgcn_global_load_lds((AS1 void*)ga, (AS3 void*)&As[(w * 32 + i * 8) * 64], 16, 0, 0);
            }
        }
        for (int i = 0; i < 4; i++) {
            const ushort_t* gb = Bbase + (size_t)(i * 8 + lrow) * K + k0 + lcol8;
            __builtin_amdgcn_global_load_lds((AS1 void*)gb, (AS3 void*)&Bs[(w * 32 + i * 8) * 64], 16, 0, 0);
        }
        __syncthreads();
        for (int kt = 0; kt < 2; kt++) {
            short8 af[4], bf[4];
            for (int m = 0; m < 4; m++)
                af[m] = *(const short8*)&As[(wM * 64 + m * 16 + l15) * 64 + kt * 32 + quad * 8];
            for (int n = 0; n < 4; n++)
                bf[n] = *(const short8*)&Bs[(wN * 64 + n * 16 + l15) * 64 + kt * 32 + quad * 8];
            for (int m = 0; m < 4; m++)
                for (int n = 0; n < 4; n++)
                    acc[m][n] = __builtin_amdgcn_mfma_f32_16x16x32_bf16(af[m], bf[n], acc[m][n], 0, 0, 0);
        }
    }

    if (EPI == 0) {
        for (int m = 0; m < 4; m++) {
            int gm = tM + wM * 64 + m * 16 + quad * 4;
            for (int n = 0; n < 4; n++) {
                int gn = tN + wN * 64 + n * 16 + l15;
                int three = gn >> 10;
                int h = (gn >> 6) & 15;
                int dd = gn & 63;
                ushort_t* dst = (three == 0) ? outQ : (three == 1) ? outK : outV;
                for (int r = 0; r < 4; r++) {
                    int row = gm + r;
                    int b = row >> 11;
                    int ns = row & 2047;
                    dst[(((size_t)(b * 16 + h) * 2048 + ns) << 6) + dd] = f2bf(acc[m][n][r]);
                }
            }
        }
    } else {
        for (int m = 0; m < 4; m++) {
            int gm = tM + wM * 64 + m * 16 + quad * 4;
            for (int n = 0; n < 4; n++) {
                int gn = tN + wN * 64 + n * 16 + l15;
                float bv = bias[gn];
                for (int r = 0; r < 4; r++)
                    outC[(size_t)(gm + r) * N + gn] = acc[m][n][r] + bv;
            }
        }
    }
}

// ---------- flash attention, fixed-offset deferred softmax ----------
// q,k,v: [BH][N][d] bf16; out: [B][N][H*d] bf16
__global__ __launch_bounds__(256) void attn_kernel(
    const ushort_t* __restrict__ q, const ushort_t* __restrict__ k,
    const ushort_t* __restrict__ v, const int* __restrict__ pad,
    const int* __restrict__ csp, ushort_t* __restrict__ out) {
    __shared__ __align__(16) ushort_t Ks[64 * 64];   // [key][dd], XOR-swizzled
    __shared__ __align__(16) ushort_t VsT[64 * 64];  // [dd][key], XOR-swizzled
    __shared__ __align__(16) ushort_t Ps[4][16 * 64];// per-wave [qrow][key], swizzled
    __shared__ float padb[2048];

    int cs = csp[0];
    int t = threadIdx.x, w = t >> 6, lane = t & 63;
    int quad = lane >> 4, l15 = lane & 15;
    int bh = blockIdx.y;
    int b = bh >> 4, h = bh & 15;
    int qt = 31 - (int)blockIdx.x;   // heavy tiles first
    int q0 = qt * 64;
    const float c1 = 0.18033688f;    // 0.125 * log2(e)
    const float c2 = -11.541560f;    // -8 * log2(e)  (fixed softmax offset)

    // padding-bias table: c2 folded in; -1e38 -> exp2 -> 0
    for (int i = 0; i < 8; i++) {
        int key = t + i * 256;
        padb[key] = pad[b * 2048 + key] ? -1e38f : c2;
    }

    const ushort_t* qbase = q + ((size_t)bh * 2048 + q0 + w * 16 + l15) * 64;
    short8 qf0 = *(const short8*)(qbase + quad * 8);
    short8 qf1 = *(const short8*)(qbase + 32 + quad * 8);

    float4_t O[4];
    for (int i = 0; i < 4; i++) O[i] = (float4_t){0.f, 0.f, 0.f, 0.f};
    float lsum[4] = {0.f, 0.f, 0.f, 0.f};

    int csT = (cs + 63) >> 6;
    int nT = qt + 1; if (csT > nT) nT = csT;

    const ushort_t* kbase = k + (size_t)bh * 2048 * 64;
    const ushort_t* vbase = v + (size_t)bh * 2048 * 64;

    int lrow = lane >> 3, lblk = lane & 7;
    int prow = q0 + w * 16 + quad * 4;
    int sw = l15 & 7;   // row&7 for all frag reads (rows = X*16 + l15)

    for (int it = 0; it < nT; it++) {
        int k0 = it * 64;
        __syncthreads();
        // K tile [key][dd] via global_load_lds, source-block XOR'd to effect swizzle
        for (int i = 0; i < 2; i++) {
            int brow = w * 16 + i * 8;
            int row = brow + lrow;
            const ushort_t* gk = kbase + (size_t)(k0 + row) * 64 + ((lblk ^ lrow) * 8);
            __builtin_amdgcn_global_load_lds((AS1 void*)gk, (AS3 void*)&Ks[brow * 64], 16, 0, 0);
        }
        // V^T tile: lanes-over-keys strided global read, swizzled b16 LDS writes
        for (int i = 0; i < 2; i++) {
            int c = w + i * 4;  // dd chunk 0..7
            short8 vr = *(const short8*)(vbase + (size_t)(k0 + lane) * 64 + c * 8);
            for (int j = 0; j < 8; j++) {
                int dd = c * 8 + j;
                VsT[dd * 64 + (((lane >> 3) ^ j) * 8) + (lane & 7)] = (ushort_t)vr[j];
            }
        }
        __syncthreads();

        bool needC = (it >= qt) && (k0 + 63 >= cs);

        // S = Q K^T
        float4_t s[4];
        for (int ks = 0; ks < 4; ks++) {
            float4_t a = (float4_t){0.f, 0.f, 0.f, 0.f};
            const ushort_t* krow = &Ks[(ks * 16 + l15) * 64];
            short8 kf0 = *(const short8*)(krow + (quad ^ sw) * 8);
            short8 kf1 = *(const short8*)(krow + ((4 + quad) ^ sw) * 8);
            a = __builtin_amdgcn_mfma_f32_16x16x32_bf16(qf0, kf0, a, 0, 0, 0);
            a = __builtin_amdgcn_mfma_f32_16x16x32_bf16(qf1, kf1, a, 0, 0, 0);
            s[ks] = a;
        }
        // p = 2^(s*c1 + padb[key]); no max-tracking, no rescale, no shuffles
        for (int ks = 0; ks < 4; ks++) {
            int key = k0 + ks * 16 + l15;
            float add = padb[key];
            for (int r = 0; r < 4; r++) {
                float arg = s[ks][r] * c1 + add;
                if (needC && (key > prow + r) && (key >= cs)) arg = -1e38f;
                float p = __builtin_amdgcn_exp2f(arg);
                lsum[r] += p;
                int row = quad * 4 + r;
                Ps[w][row * 64 + (((ks * 2 + (l15 >> 3)) ^ (row & 7)) * 8) + (l15 & 7)] = f2bf(p);
            }
        }
        // O += P V  (P per-wave: in-wave LDS ordering, no barrier needed)
        const ushort_t* prl = &Ps[w][l15 * 64];
        short8 pf0 = *(const short8*)(prl + (quad ^ sw) * 8);
        short8 pf1 = *(const short8*)(prl + ((4 + quad) ^ sw) * 8);
        for (int n = 0; n < 4; n++) {
            const ushort_t* vrow = &VsT[(n * 16 + l15) * 64];
            short8 vf0 = *(const short8*)(vrow + (quad ^ sw) * 8);
            short8 vf1 = *(const short8*)(vrow + ((4 + quad) ^ sw) * 8);
            O[n] = __builtin_amdgcn_mfma_f32_16x16x32_bf16(pf0, vf0, O[n], 0, 0, 0);
            O[n] = __builtin_amdgcn_mfma_f32_16x16x32_bf16(pf1, vf1, O[n], 0, 0, 0);
        }
    }

    // one-time l reduction across the 16 key-lanes, normalize, store
    for (int r = 0; r < 4; r++) {
        float l = lsum[r];
        l += __shfl_xor(l, 1, 64);
        l += __shfl_xor(l, 2, 64);
        l += __shfl_xor(l, 4, 64);
        l += __shfl_xor(l, 8, 64);
        float inv = l > 0.f ? 1.f / l : 0.f;
        int row = q0 + w * 16 + quad * 4 + r;
        size_t ob = ((size_t)b * 2048 + row) * 1024 + h * 64;
        for (int n = 0; n < 4; n++)
            out[ob + n * 16 + l15] = f2bf(O[n][r] * inv);
    }
}

extern "C" void kernel_launch(void* const* d_in, const int* in_sizes, int n_in,
                              void* d_out, int out_size, void* d_ws, size_t ws_size,
                              hipStream_t stream) {
    const float* x = (const float*)d_in[0];
    const int* pad = (const int*)d_in[1];
    const int* cs = (const int*)d_in[2];
    const float* wqkv = (const float*)d_in[3];
    const float* wproj = (const float*)d_in[4];
    const float* bproj = (const float*)d_in[5];
    float* out = (float*)d_out;

    // ws layout, peak 32 MB via lifetime aliasing (units: ushort):
    //   q[0,4M) k[4M,8M) v[8M,12M)   (all [b,h,n,d])
    //   wqkvT[12M,15M) dies after gemm1; ao[12M,16M) after attn
    //   wprojT[0,1M) after q dies
    ushort_t* ws = (ushort_t*)d_ws;
    ushort_t* qws = ws;
    ushort_t* kws = ws + (size_t)4194304;
    ushort_t* vws = ws + (size_t)8388608;
    ushort_t* wqkvT = ws + (size_t)12582912;
    ushort_t* aows = ws + (size_t)12582912;
    ushort_t* wprojT = ws;

    transpose_f32_bf16<<<dim3(48, 16), 256, 0, stream>>>(wqkv, wqkvT, 1024, 3072);
    gemm_bt<0, 1><<<dim3(24, 32), 256, 0, stream>>>(x, wqkvT, 4096, 3072, 1024,
                                                    qws, kws, vws, nullptr, nullptr);
    attn_kernel<<<dim3(32, 32), 256, 0, stream>>>(qws, kws, vws, pad, cs, aows);
    transpose_f32_bf16<<<dim3(16, 16), 256, 0, stream>>>(wproj, wprojT, 1024, 1024);
    gemm_bt<1, 0><<<dim3(8, 32), 256, 0, stream>>>(aows, wprojT, 4096, 1024, 1024,
                                                   nullptr, nullptr, nullptr, bproj, out);
}

// Round 5
// 228.311 us; speedup vs baseline: 1.4969x; 1.1012x over previous
//
#include <hip/hip_runtime.h>
#include <stdint.h>

typedef unsigned short ushort_t;
typedef __attribute__((ext_vector_type(4))) unsigned short ushort4_t;
typedef __attribute__((ext_vector_type(8))) short short8;
typedef __attribute__((ext_vector_type(4))) float float4_t;

#define AS1 __attribute__((address_space(1)))
#define AS3 __attribute__((address_space(3)))

__device__ inline ushort_t f2bf(float f) {
    unsigned x = __builtin_bit_cast(unsigned, f);
    unsigned r = x + 0x7fffu + ((x >> 16) & 1u);
    return (ushort_t)(r >> 16);
}

// ---------- elementwise convert fp32 -> bf16 (8 elems/thread) ----------
__global__ __launch_bounds__(256) void convert_f32_bf16(const float* __restrict__ in,
                                                        ushort_t* __restrict__ out) {
    size_t i = ((size_t)blockIdx.x * 256 + threadIdx.x) * 8;
    float4_t a = *(const float4_t*)(in + i);
    float4_t b = *(const float4_t*)(in + i + 4);
    ushort_t u[8];
    u[0] = f2bf(a.x); u[1] = f2bf(a.y); u[2] = f2bf(a.z); u[3] = f2bf(a.w);
    u[4] = f2bf(b.x); u[5] = f2bf(b.y); u[6] = f2bf(b.z); u[7] = f2bf(b.w);
    *(ushort4_t*)(out + i) = *(ushort4_t*)&u[0];
    *(ushort4_t*)(out + i + 4) = *(ushort4_t*)&u[4];
}

// ---------- transpose+convert: in fp32 [R][C] -> out bf16 [C][R] ----------
__global__ __launch_bounds__(256) void transpose_f32_bf16(const float* __restrict__ in,
                                                          ushort_t* __restrict__ out,
                                                          int R, int C) {
    __shared__ __align__(16) ushort_t tile[64][65];
    int c0 = blockIdx.x * 64, r0 = blockIdx.y * 64;
    int t = threadIdx.x;
    for (int i = 0; i < 16; i++) {
        int idx = t + i * 256;
        int lr = idx >> 6, lc = idx & 63;
        tile[lr][lc] = f2bf(in[(size_t)(r0 + lr) * C + c0 + lc]);
    }
    __syncthreads();
    for (int i = 0; i < 16; i++) {
        int idx = t + i * 256;
        int lr = idx >> 6, lc = idx & 63;
        out[(size_t)(c0 + lr) * R + r0 + lc] = tile[lc][lr];
    }
}

// ---------- GEMM: C[M][N] = A[M][K] @ Bt[N][K]^T, bf16 MFMA ----------
template <int EPI, int AFP32>
__global__ __launch_bounds__(256) void gemm_bt(
    const void* __restrict__ Ap, const ushort_t* __restrict__ Bt,
    int M, int N, int K,
    ushort_t* __restrict__ outQ, ushort_t* __restrict__ outK, ushort_t* __restrict__ outV,
    const float* __restrict__ bias, float* __restrict__ outC) {
    __shared__ __align__(16) ushort_t As[128 * 64];
    __shared__ __align__(16) ushort_t Bs[128 * 64];
    int t = threadIdx.x;
    int w = t >> 6, lane = t & 63;
    int quad = lane >> 4, l15 = lane & 15;
    int wM = w >> 1, wN = w & 1;
    int tM = blockIdx.y * 128, tN = blockIdx.x * 128;

    float4_t acc[4][4];
    for (int i = 0; i < 4; i++)
        for (int j = 0; j < 4; j++) acc[i][j] = (float4_t){0.f, 0.f, 0.f, 0.f};

    int lrow = lane >> 3;
    int lcol8 = (lane & 7) * 8;

    const ushort_t* Abf = (const ushort_t*)Ap;
    const float* Afp = (const float*)Ap;
    const ushort_t* Bbase = Bt + (size_t)(tN + w * 32) * K;

    for (int k0 = 0; k0 < K; k0 += 64) {
        __syncthreads();
        if (AFP32) {
            for (int i = 0; i < 8; i++) {
                int e = t + i * 256;
                int row = e >> 4, c4 = (e & 15) * 4;
                const float4_t f = *(const float4_t*)&Afp[(size_t)(tM + row) * K + k0 + c4];
                ushort4_t u;
                u.x = f2bf(f.x); u.y = f2bf(f.y); u.z = f2bf(f.z); u.w = f2bf(f.w);
                *(ushort4_t*)&As[row * 64 + c4] = u;
            }
        } else {
            const ushort_t* Abase = Abf + (size_t)(tM + w * 32) * K;
            for (int i = 0; i < 4; i++) {
                const ushort_t* ga = Abase + (size_t)(i * 8 + lrow) * K + k0 + lcol8;
                __builtin_amdgcn_global_load_lds((AS1 void*)ga, (AS3 void*)&As[(w * 32 + i * 8) * 64], 16, 0, 0);
            }
        }
        for (int i = 0; i < 4; i++) {
            const ushort_t* gb = Bbase + (size_t)(i * 8 + lrow) * K + k0 + lcol8;
            __builtin_amdgcn_global_load_lds((AS1 void*)gb, (AS3 void*)&Bs[(w * 32 + i * 8) * 64], 16, 0, 0);
        }
        __syncthreads();
        for (int kt = 0; kt < 2; kt++) {
            short8 af[4], bf[4];
            for (int m = 0; m < 4; m++)
                af[m] = *(const short8*)&As[(wM * 64 + m * 16 + l15) * 64 + kt * 32 + quad * 8];
            for (int n = 0; n < 4; n++)
                bf[n] = *(const short8*)&Bs[(wN * 64 + n * 16 + l15) * 64 + kt * 32 + quad * 8];
            for (int m = 0; m < 4; m++)
                for (int n = 0; n < 4; n++)
                    acc[m][n] = __builtin_amdgcn_mfma_f32_16x16x32_bf16(af[m], bf[n], acc[m][n], 0, 0, 0);
        }
    }

    if (EPI == 0) {
        for (int m = 0; m < 4; m++) {
            int gm = tM + wM * 64 + m * 16 + quad * 4;
            for (int n = 0; n < 4; n++) {
                int gn = tN + wN * 64 + n * 16 + l15;
                int three = gn >> 10;
                int h = (gn >> 6) & 15;
                int dd = gn & 63;
                ushort_t* dst = (three == 0) ? outQ : (three == 1) ? outK : outV;
                for (int r = 0; r < 4; r++) {
                    int row = gm + r;
                    int b = row >> 11;
                    int ns = row & 2047;
                    dst[(((size_t)(b * 16 + h) * 2048 + ns) << 6) + dd] = f2bf(acc[m][n][r]);
                }
            }
        }
    } else {
        for (int m = 0; m < 4; m++) {
            int gm = tM + wM * 64 + m * 16 + quad * 4;
            for (int n = 0; n < 4; n++) {
                int gn = tN + wN * 64 + n * 16 + l15;
                float bv = bias[gn];
                for (int r = 0; r < 4; r++)
                    outC[(size_t)(gm + r) * N + gn] = acc[m][n][r] + bv;
            }
        }
    }
}

// ---------- flash attention: paired q-tiles over shared key loop ----------
// q,k,v: [BH][N][d] bf16; out: [B][N][H*d] bf16
// block x in [0,16): handles q-tiles qtA=31-x (heavy) and qtB=x (light);
// work/block = (32-x)+(x+1) ~ 33 tile-units -> uniform per-CU load.
__global__ __launch_bounds__(256) void attn_kernel(
    const ushort_t* __restrict__ q, const ushort_t* __restrict__ k,
    const ushort_t* __restrict__ v, const int* __restrict__ pad,
    const int* __restrict__ csp, ushort_t* __restrict__ out) {
    __shared__ __align__(16) ushort_t Ks[64 * 64];      // [key][dd], XOR-swizzled
    __shared__ __align__(16) ushort_t VsT[64 * 64];     // [dd][key], XOR-swizzled
    __shared__ __align__(16) ushort_t Ps[4][2][16 * 64];// per-wave, per-tile
    __shared__ float padb[2048];

    int cs = csp[0];
    int t = threadIdx.x, w = t >> 6, lane = t & 63;
    int quad = lane >> 4, l15 = lane & 15;
    int bh = blockIdx.y;
    int b = bh >> 4, h = bh & 15;
    int xp = blockIdx.x;
    int qtA = 31 - xp, qtB = xp;
    int q0A = qtA * 64, q0B = qtB * 64;
    const float c1 = 0.18033688f;    // 0.125 * log2(e)
    const float c2 = -11.541560f;    // -8 * log2(e)  (fixed softmax offset)

    for (int i = 0; i < 8; i++) {
        int key = t + i * 256;
        padb[key] = pad[b * 2048 + key] ? -1e38f : c2;
    }

    const ushort_t* qbA = q + ((size_t)bh * 2048 + q0A + w * 16 + l15) * 64;
    short8 qA0 = *(const short8*)(qbA + quad * 8);
    short8 qA1 = *(const short8*)(qbA + 32 + quad * 8);
    const ushort_t* qbB = q + ((size_t)bh * 2048 + q0B + w * 16 + l15) * 64;
    short8 qB0 = *(const short8*)(qbB + quad * 8);
    short8 qB1 = *(const short8*)(qbB + 32 + quad * 8);

    float4_t OA[4], OB[4];
    for (int i = 0; i < 4; i++) { OA[i] = (float4_t){0.f,0.f,0.f,0.f}; OB[i] = (float4_t){0.f,0.f,0.f,0.f}; }
    float lsA[4] = {0.f,0.f,0.f,0.f}, lsB[4] = {0.f,0.f,0.f,0.f};

    int csT = (cs + 63) >> 6;
    int nTA = qtA + 1; if (csT > nTA) nTA = csT;
    int nTB = qtB + 1; if (csT > nTB) nTB = csT;
    int nTmax = nTA > nTB ? nTA : nTB;

    const ushort_t* kbase = k + (size_t)bh * 2048 * 64;
    const ushort_t* vbase = v + (size_t)bh * 2048 * 64;

    int lrow = lane >> 3, lblk = lane & 7;
    int prowA = q0A + w * 16 + quad * 4;
    int prowB = q0B + w * 16 + quad * 4;
    int sw = l15 & 7;

    for (int it = 0; it < nTmax; it++) {
        int k0 = it * 64;
        __syncthreads();
        for (int i = 0; i < 2; i++) {
            int brow = w * 16 + i * 8;
            int row = brow + lrow;
            const ushort_t* gk = kbase + (size_t)(k0 + row) * 64 + ((lblk ^ lrow) * 8);
            __builtin_amdgcn_global_load_lds((AS1 void*)gk, (AS3 void*)&Ks[brow * 64], 16, 0, 0);
        }
        for (int i = 0; i < 2; i++) {
            int c = w + i * 4;
            short8 vr = *(const short8*)(vbase + (size_t)(k0 + lane) * 64 + c * 8);
            for (int j = 0; j < 8; j++) {
                int dd = c * 8 + j;
                VsT[dd * 64 + (((lane >> 3) ^ j) * 8) + (lane & 7)] = (ushort_t)vr[j];
            }
        }
        __syncthreads();

        bool actA = it < nTA, actB = it < nTB;

        // K frags loaded once, shared by both q-tiles
        short8 kf0[4], kf1[4];
        for (int ks = 0; ks < 4; ks++) {
            const ushort_t* krow = &Ks[(ks * 16 + l15) * 64];
            kf0[ks] = *(const short8*)(krow + (quad ^ sw) * 8);
            kf1[ks] = *(const short8*)(krow + ((4 + quad) ^ sw) * 8);
        }

        if (actA) {
            float4_t s[4];
            for (int ks = 0; ks < 4; ks++) {
                float4_t a = (float4_t){0.f,0.f,0.f,0.f};
                a = __builtin_amdgcn_mfma_f32_16x16x32_bf16(qA0, kf0[ks], a, 0, 0, 0);
                a = __builtin_amdgcn_mfma_f32_16x16x32_bf16(qA1, kf1[ks], a, 0, 0, 0);
                s[ks] = a;
            }
            bool needC = (it >= qtA) && (k0 + 63 >= cs);
            for (int ks = 0; ks < 4; ks++) {
                int key = k0 + ks * 16 + l15;
                float add = padb[key];
                for (int r = 0; r < 4; r++) {
                    float arg = s[ks][r] * c1 + add;
                    if (needC && (key > prowA + r) && (key >= cs)) arg = -1e38f;
                    float p = __builtin_amdgcn_exp2f(arg);
                    lsA[r] += p;
                    int row = quad * 4 + r;
                    Ps[w][0][row * 64 + (((ks * 2 + (l15 >> 3)) ^ (row & 7)) * 8) + (l15 & 7)] = f2bf(p);
                }
            }
        }
        if (actB) {
            float4_t s[4];
            for (int ks = 0; ks < 4; ks++) {
                float4_t a = (float4_t){0.f,0.f,0.f,0.f};
                a = __builtin_amdgcn_mfma_f32_16x16x32_bf16(qB0, kf0[ks], a, 0, 0, 0);
                a = __builtin_amdgcn_mfma_f32_16x16x32_bf16(qB1, kf1[ks], a, 0, 0, 0);
                s[ks] = a;
            }
            bool needC = (it >= qtB) && (k0 + 63 >= cs);
            for (int ks = 0; ks < 4; ks++) {
                int key = k0 + ks * 16 + l15;
                float add = padb[key];
                for (int r = 0; r < 4; r++) {
                    float arg = s[ks][r] * c1 + add;
                    if (needC && (key > prowB + r) && (key >= cs)) arg = -1e38f;
                    float p = __builtin_amdgcn_exp2f(arg);
                    lsB[r] += p;
                    int row = quad * 4 + r;
                    Ps[w][1][row * 64 + (((ks * 2 + (l15 >> 3)) ^ (row & 7)) * 8) + (l15 & 7)] = f2bf(p);
                }
            }
        }

        // V frags loaded once, shared
        short8 vf0[4], vf1[4];
        for (int n = 0; n < 4; n++) {
            const ushort_t* vrow = &VsT[(n * 16 + l15) * 64];
            vf0[n] = *(const short8*)(vrow + (quad ^ sw) * 8);
            vf1[n] = *(const short8*)(vrow + ((4 + quad) ^ sw) * 8);
        }
        if (actA) {
            const ushort_t* prl = &Ps[w][0][l15 * 64];
            short8 pf0 = *(const short8*)(prl + (quad ^ sw) * 8);
            short8 pf1 = *(const short8*)(prl + ((4 + quad) ^ sw) * 8);
            for (int n = 0; n < 4; n++) {
                OA[n] = __builtin_amdgcn_mfma_f32_16x16x32_bf16(pf0, vf0[n], OA[n], 0, 0, 0);
                OA[n] = __builtin_amdgcn_mfma_f32_16x16x32_bf16(pf1, vf1[n], OA[n], 0, 0, 0);
            }
        }
        if (actB) {
            const ushort_t* prl = &Ps[w][1][l15 * 64];
            short8 pf0 = *(const short8*)(prl + (quad ^ sw) * 8);
            short8 pf1 = *(const short8*)(prl + ((4 + quad) ^ sw) * 8);
            for (int n = 0; n < 4; n++) {
                OB[n] = __builtin_amdgcn_mfma_f32_16x16x32_bf16(pf0, vf0[n], OB[n], 0, 0, 0);
                OB[n] = __builtin_amdgcn_mfma_f32_16x16x32_bf16(pf1, vf1[n], OB[n], 0, 0, 0);
            }
        }
    }

    for (int r = 0; r < 4; r++) {
        float l = lsA[r];
        l += __shfl_xor(l, 1, 64); l += __shfl_xor(l, 2, 64);
        l += __shfl_xor(l, 4, 64); l += __shfl_xor(l, 8, 64);
        float inv = l > 0.f ? 1.f / l : 0.f;
        int row = q0A + w * 16 + quad * 4 + r;
        size_t ob = ((size_t)b * 2048 + row) * 1024 + h * 64;
        for (int n = 0; n < 4; n++)
            out[ob + n * 16 + l15] = f2bf(OA[n][r] * inv);
    }
    for (int r = 0; r < 4; r++) {
        float l = lsB[r];
        l += __shfl_xor(l, 1, 64); l += __shfl_xor(l, 2, 64);
        l += __shfl_xor(l, 4, 64); l += __shfl_xor(l, 8, 64);
        float inv = l > 0.f ? 1.f / l : 0.f;
        int row = q0B + w * 16 + quad * 4 + r;
        size_t ob = ((size_t)b * 2048 + row) * 1024 + h * 64;
        for (int n = 0; n < 4; n++)
            out[ob + n * 16 + l15] = f2bf(OB[n][r] * inv);
    }
}

extern "C" void kernel_launch(void* const* d_in, const int* in_sizes, int n_in,
                              void* d_out, int out_size, void* d_ws, size_t ws_size,
                              hipStream_t stream) {
    const float* x = (const float*)d_in[0];
    const int* pad = (const int*)d_in[1];
    const int* cs = (const int*)d_in[2];
    const float* wqkv = (const float*)d_in[3];
    const float* wproj = (const float*)d_in[4];
    const float* bproj = (const float*)d_in[5];
    float* out = (float*)d_out;

    // base layout (peak 32 MB): q[0,4M) k[4,8M) v[8,12M) ushorts;
    // wqkvT[12M,15M) dies after gemm1; ao[12M,16M); wprojT[0,1M) after q dies.
    // big layout (ws >= 40 MB): + xbf[16M,20M) -> gemm1 uses global_load_lds A-path.
    ushort_t* ws = (ushort_t*)d_ws;
    ushort_t* qws = ws;
    ushort_t* kws = ws + (size_t)4194304;
    ushort_t* vws = ws + (size_t)8388608;
    ushort_t* wqkvT = ws + (size_t)12582912;
    ushort_t* aows = ws + (size_t)12582912;
    ushort_t* wprojT = ws;
    ushort_t* xbf = ws + (size_t)16777216;

    bool big = ws_size >= (size_t)40 * 1024 * 1024;

    transpose_f32_bf16<<<dim3(48, 16), 256, 0, stream>>>(wqkv, wqkvT, 1024, 3072);
    if (big) {
        convert_f32_bf16<<<2048, 256, 0, stream>>>(x, xbf);   // 4M elems, 8/thread
        gemm_bt<0, 0><<<dim3(24, 32), 256, 0, stream>>>(xbf, wqkvT, 4096, 3072, 1024,
                                                        qws, kws, vws, nullptr, nullptr);
    } else {
        gemm_bt<0, 1><<<dim3(24, 32), 256, 0, stream>>>(x, wqkvT, 4096, 3072, 1024,
                                                        qws, kws, vws, nullptr, nullptr);
    }
    attn_kernel<<<dim3(16, 32), 256, 0, stream>>>(qws, kws, vws, pad, cs, aows);
    transpose_f32_bf16<<<dim3(16, 16), 256, 0, stream>>>(wproj, wprojT, 1024, 1024);
    gemm_bt<1, 0><<<dim3(8, 32), 256, 0, stream>>>(aows, wprojT, 4096, 1024, 1024,
                                                   nullptr, nullptr, nullptr, bproj, out);
}

// Round 6
// 223.475 us; speedup vs baseline: 1.5293x; 1.0216x over previous
//
#include <hip/hip_runtime.h>
#include <stdint.h>

typedef unsigned short ushort_t;
typedef __attribute__((ext_vector_type(4))) unsigned short ushort4_t;
typedef __attribute__((ext_vector_type(8))) short short8;
typedef __attribute__((ext_vector_type(4))) float float4_t;

#define AS1 __attribute__((address_space(1)))
#define AS3 __attribute__((address_space(3)))

__device__ inline ushort_t f2bf(float f) {
    unsigned x = __builtin_bit_cast(unsigned, f);
    unsigned r = x + 0x7fffu + ((x >> 16) & 1u);
    return (ushort_t)(r >> 16);
}
__device__ inline ushort_t f2bf_trunc(float f) {
    return (ushort_t)(__builtin_bit_cast(unsigned, f) >> 16);
}

// ---------- elementwise convert fp32 -> bf16 (8 elems/thread) ----------
__global__ __launch_bounds__(256) void convert_f32_bf16(const float* __restrict__ in,
                                                        ushort_t* __restrict__ out) {
    size_t i = ((size_t)blockIdx.x * 256 + threadIdx.x) * 8;
    float4_t a = *(const float4_t*)(in + i);
    float4_t b = *(const float4_t*)(in + i + 4);
    ushort_t u[8];
    u[0] = f2bf(a.x); u[1] = f2bf(a.y); u[2] = f2bf(a.z); u[3] = f2bf(a.w);
    u[4] = f2bf(b.x); u[5] = f2bf(b.y); u[6] = f2bf(b.z); u[7] = f2bf(b.w);
    *(ushort4_t*)(out + i) = *(ushort4_t*)&u[0];
    *(ushort4_t*)(out + i + 4) = *(ushort4_t*)&u[4];
}

// ---------- transpose+convert: in fp32 [R][C] -> out bf16 [C][R] ----------
__global__ __launch_bounds__(256) void transpose_f32_bf16(const float* __restrict__ in,
                                                          ushort_t* __restrict__ out,
                                                          int R, int C) {
    __shared__ __align__(16) ushort_t tile[64][65];
    int c0 = blockIdx.x * 64, r0 = blockIdx.y * 64;
    int t = threadIdx.x;
    for (int i = 0; i < 16; i++) {
        int idx = t + i * 256;
        int lr = idx >> 6, lc = idx & 63;
        tile[lr][lc] = f2bf(in[(size_t)(r0 + lr) * C + c0 + lc]);
    }
    __syncthreads();
    for (int i = 0; i < 16; i++) {
        int idx = t + i * 256;
        int lr = idx >> 6, lc = idx & 63;
        out[(size_t)(c0 + lr) * R + r0 + lc] = tile[lc][lr];
    }
}

// ---------- GEMM: C[M][N] = A[M][K] @ Bt[N][K]^T, bf16 MFMA, glds staging ----------
// EPI=0: scatter bf16 to q/k/v ([b,h,n,d]).  EPI=1: add fp32 bias, write fp32 out.
template <int EPI>
__global__ __launch_bounds__(256) void gemm_bt(
    const ushort_t* __restrict__ A, const ushort_t* __restrict__ Bt,
    int M, int N, int K,
    ushort_t* __restrict__ outQ, ushort_t* __restrict__ outK, ushort_t* __restrict__ outV,
    const float* __restrict__ bias, float* __restrict__ outC) {
    __shared__ __align__(16) ushort_t As[128 * 64];
    __shared__ __align__(16) ushort_t Bs[128 * 64];
    int t = threadIdx.x;
    int w = t >> 6, lane = t & 63;
    int quad = lane >> 4, l15 = lane & 15;
    int wM = w >> 1, wN = w & 1;
    int tM = blockIdx.y * 128, tN = blockIdx.x * 128;

    float4_t acc[4][4];
    for (int i = 0; i < 4; i++)
        for (int j = 0; j < 4; j++) acc[i][j] = (float4_t){0.f, 0.f, 0.f, 0.f};

    int lrow = lane >> 3;
    int lcol8 = (lane & 7) * 8;

    const ushort_t* Abase = A + (size_t)(tM + w * 32) * K;
    const ushort_t* Bbase = Bt + (size_t)(tN + w * 32) * K;

    for (int k0 = 0; k0 < K; k0 += 64) {
        __syncthreads();
        for (int i = 0; i < 4; i++) {
            const ushort_t* ga = Abase + (size_t)(i * 8 + lrow) * K + k0 + lcol8;
            __builtin_amdgcn_global_load_lds((AS1 void*)ga, (AS3 void*)&As[(w * 32 + i * 8) * 64], 16, 0, 0);
            const ushort_t* gb = Bbase + (size_t)(i * 8 + lrow) * K + k0 + lcol8;
            __builtin_amdgcn_global_load_lds((AS1 void*)gb, (AS3 void*)&Bs[(w * 32 + i * 8) * 64], 16, 0, 0);
        }
        __syncthreads();
        for (int kt = 0; kt < 2; kt++) {
            short8 af[4], bf[4];
            for (int m = 0; m < 4; m++)
                af[m] = *(const short8*)&As[(wM * 64 + m * 16 + l15) * 64 + kt * 32 + quad * 8];
            for (int n = 0; n < 4; n++)
                bf[n] = *(const short8*)&Bs[(wN * 64 + n * 16 + l15) * 64 + kt * 32 + quad * 8];
            for (int m = 0; m < 4; m++)
                for (int n = 0; n < 4; n++)
                    acc[m][n] = __builtin_amdgcn_mfma_f32_16x16x32_bf16(af[m], bf[n], acc[m][n], 0, 0, 0);
        }
    }

    if (EPI == 0) {
        for (int m = 0; m < 4; m++) {
            int gm = tM + wM * 64 + m * 16 + quad * 4;
            for (int n = 0; n < 4; n++) {
                int gn = tN + wN * 64 + n * 16 + l15;
                int three = gn >> 10;
                int h = (gn >> 6) & 15;
                int dd = gn & 63;
                ushort_t* dst = (three == 0) ? outQ : (three == 1) ? outK : outV;
                for (int r = 0; r < 4; r++) {
                    int row = gm + r;
                    int b = row >> 11;
                    int ns = row & 2047;
                    dst[(((size_t)(b * 16 + h) * 2048 + ns) << 6) + dd] = f2bf(acc[m][n][r]);
                }
            }
        }
    } else {
        for (int m = 0; m < 4; m++) {
            int gm = tM + wM * 64 + m * 16 + quad * 4;
            for (int n = 0; n < 4; n++) {
                int gn = tN + wN * 64 + n * 16 + l15;
                float bv = bias[gn];
                for (int r = 0; r < 4; r++)
                    outC[(size_t)(gm + r) * N + gn] = acc[m][n][r] + bv;
            }
        }
    }
}

// ---------- flash attention: paired q-tiles, deferred softmax, K/V double-buffer ----------
// q,k,v: [BH][N][d] bf16; out: [B][N][H*d] bf16
__global__ __launch_bounds__(256) void attn_kernel(
    const ushort_t* __restrict__ q, const ushort_t* __restrict__ k,
    const ushort_t* __restrict__ v, const int* __restrict__ pad,
    const int* __restrict__ csp, ushort_t* __restrict__ out) {
    __shared__ __align__(16) ushort_t Ks[2][64 * 64];    // [key][dd], XOR-swizzled
    __shared__ __align__(16) ushort_t VsT[2][64 * 64];   // [dd][key], XOR-swizzled
    __shared__ __align__(16) ushort_t Ps[4][2][16 * 64]; // per-wave, per-tile
    __shared__ float padb[2048];

    int cs = csp[0];
    int t = threadIdx.x, w = t >> 6, lane = t & 63;
    int quad = lane >> 4, l15 = lane & 15;
    int bh = blockIdx.y;
    int b = bh >> 4, h = bh & 15;
    int xp = blockIdx.x;
    int qtA = 31 - xp, qtB = xp;
    int q0A = qtA * 64, q0B = qtB * 64;
    const float c1 = 0.18033688f;    // 0.125 * log2(e)
    const float c2 = -11.541560f;    // -8 * log2(e)

    for (int i = 0; i < 8; i++) {
        int key = t + i * 256;
        padb[key] = pad[b * 2048 + key] ? -1e38f : c2;
    }

    const ushort_t* qbA = q + ((size_t)bh * 2048 + q0A + w * 16 + l15) * 64;
    short8 qA0 = *(const short8*)(qbA + quad * 8);
    short8 qA1 = *(const short8*)(qbA + 32 + quad * 8);
    const ushort_t* qbB = q + ((size_t)bh * 2048 + q0B + w * 16 + l15) * 64;
    short8 qB0 = *(const short8*)(qbB + quad * 8);
    short8 qB1 = *(const short8*)(qbB + 32 + quad * 8);

    float4_t OA[4], OB[4];
    for (int i = 0; i < 4; i++) { OA[i] = (float4_t){0.f,0.f,0.f,0.f}; OB[i] = (float4_t){0.f,0.f,0.f,0.f}; }
    float lsA[4] = {0.f,0.f,0.f,0.f}, lsB[4] = {0.f,0.f,0.f,0.f};

    int csT = (cs + 63) >> 6;
    int nTA = qtA + 1; if (csT > nTA) nTA = csT;
    int nTB = qtB + 1; if (csT > nTB) nTB = csT;
    int nTmax = nTA > nTB ? nTA : nTB;

    const ushort_t* kbase = k + (size_t)bh * 2048 * 64;
    const ushort_t* vbase = v + (size_t)bh * 2048 * 64;

    int lrow = lane >> 3, lblk = lane & 7;
    int prowA = q0A + w * 16 + quad * 4;
    int prowB = q0B + w * 16 + quad * 4;
    int sw = l15 & 7;

    // --- staging helpers ---
    short8 vr0, vr1;   // V register-prefetch (chunks w and w+4 of one key row)
    auto stageK = [&](int it, int buf) {
        int k0 = it * 64;
        for (int i = 0; i < 2; i++) {
            int brow = w * 16 + i * 8;
            const ushort_t* gk = kbase + (size_t)(k0 + brow + lrow) * 64 + ((lblk ^ lrow) * 8);
            __builtin_amdgcn_global_load_lds((AS1 void*)gk, (AS3 void*)&Ks[buf][brow * 64], 16, 0, 0);
        }
    };
    auto loadV = [&](int it) {
        const ushort_t* vb = vbase + (size_t)(it * 64 + lane) * 64;
        vr0 = *(const short8*)(vb + w * 8);
        vr1 = *(const short8*)(vb + (w + 4) * 8);
    };

    // prologue
    stageK(0, 0);
    loadV(0);

    for (int it = 0; it < nTmax; it++) {
        int cur = it & 1, nxt = cur ^ 1;
        // V^T write for current tile (from prefetched regs; swizzled b16)
        for (int j = 0; j < 8; j++) {
            int sl = (((lane >> 3) ^ j) * 8) + (lane & 7);
            VsT[cur][(w * 8 + j) * 64 + sl] = (ushort_t)vr0[j];
            VsT[cur][((w + 4) * 8 + j) * 64 + sl] = (ushort_t)vr1[j];
        }
        __syncthreads();  // drains this tile's K glds; VsT[cur] visible to all waves
        // prefetch next tile (outstanding across the whole compute phase)
        if (it + 1 < nTmax) {
            stageK(it + 1, nxt);
            loadV(it + 1);
        }

        int k0 = it * 64;
        bool actA = it < nTA, actB = it < nTB;

        short8 kf0[4], kf1[4];
        for (int ks = 0; ks < 4; ks++) {
            const ushort_t* krow = &Ks[cur][(ks * 16 + l15) * 64];
            kf0[ks] = *(const short8*)(krow + (quad ^ sw) * 8);
            kf1[ks] = *(const short8*)(krow + ((4 + quad) ^ sw) * 8);
        }

        if (actA) {
            float4_t s[4];
            for (int ks = 0; ks < 4; ks++) {
                float4_t a = (float4_t){0.f,0.f,0.f,0.f};
                a = __builtin_amdgcn_mfma_f32_16x16x32_bf16(qA0, kf0[ks], a, 0, 0, 0);
                a = __builtin_amdgcn_mfma_f32_16x16x32_bf16(qA1, kf1[ks], a, 0, 0, 0);
                s[ks] = a;
            }
            bool needC = (it >= qtA) && (k0 + 63 >= cs);
            for (int ks = 0; ks < 4; ks++) {
                int key = k0 + ks * 16 + l15;
                float add = padb[key];
                for (int r = 0; r < 4; r++) {
                    float arg = s[ks][r] * c1 + add;
                    if (needC && (key > prowA + r) && (key >= cs)) arg = -1e38f;
                    float p = __builtin_amdgcn_exp2f(arg);
                    lsA[r] += p;
                    int row = quad * 4 + r;
                    Ps[w][0][row * 64 + (((ks * 2 + (l15 >> 3)) ^ (row & 7)) * 8) + (l15 & 7)] = f2bf_trunc(p);
                }
            }
        }
        if (actB) {
            float4_t s[4];
            for (int ks = 0; ks < 4; ks++) {
                float4_t a = (float4_t){0.f,0.f,0.f,0.f};
                a = __builtin_amdgcn_mfma_f32_16x16x32_bf16(qB0, kf0[ks], a, 0, 0, 0);
                a = __builtin_amdgcn_mfma_f32_16x16x32_bf16(qB1, kf1[ks], a, 0, 0, 0);
                s[ks] = a;
            }
            bool needC = (it >= qtB) && (k0 + 63 >= cs);
            for (int ks = 0; ks < 4; ks++) {
                int key = k0 + ks * 16 + l15;
                float add = padb[key];
                for (int r = 0; r < 4; r++) {
                    float arg = s[ks][r] * c1 + add;
                    if (needC && (key > prowB + r) && (key >= cs)) arg = -1e38f;
                    float p = __builtin_amdgcn_exp2f(arg);
                    lsB[r] += p;
                    int row = quad * 4 + r;
                    Ps[w][1][row * 64 + (((ks * 2 + (l15 >> 3)) ^ (row & 7)) * 8) + (l15 & 7)] = f2bf_trunc(p);
                }
            }
        }

        short8 vf0[4], vf1[4];
        for (int n = 0; n < 4; n++) {
            const ushort_t* vrow = &VsT[cur][(n * 16 + l15) * 64];
            vf0[n] = *(const short8*)(vrow + (quad ^ sw) * 8);
            vf1[n] = *(const short8*)(vrow + ((4 + quad) ^ sw) * 8);
        }
        if (actA) {
            const ushort_t* prl = &Ps[w][0][l15 * 64];
            short8 pf0 = *(const short8*)(prl + (quad ^ sw) * 8);
            short8 pf1 = *(const short8*)(prl + ((4 + quad) ^ sw) * 8);
            for (int n = 0; n < 4; n++) {
                OA[n] = __builtin_amdgcn_mfma_f32_16x16x32_bf16(pf0, vf0[n], OA[n], 0, 0, 0);
                OA[n] = __builtin_amdgcn_mfma_f32_16x16x32_bf16(pf1, vf1[n], OA[n], 0, 0, 0);
            }
        }
        if (actB) {
            const ushort_t* prl = &Ps[w][1][l15 * 64];
            short8 pf0 = *(const short8*)(prl + (quad ^ sw) * 8);
            short8 pf1 = *(const short8*)(prl + ((4 + quad) ^ sw) * 8);
            for (int n = 0; n < 4; n++) {
                OB[n] = __builtin_amdgcn_mfma_f32_16x16x32_bf16(pf0, vf0[n], OB[n], 0, 0, 0);
                OB[n] = __builtin_amdgcn_mfma_f32_16x16x32_bf16(pf1, vf1[n], OB[n], 0, 0, 0);
            }
        }
    }

    for (int r = 0; r < 4; r++) {
        float l = lsA[r];
        l += __shfl_xor(l, 1, 64); l += __shfl_xor(l, 2, 64);
        l += __shfl_xor(l, 4, 64); l += __shfl_xor(l, 8, 64);
        float inv = l > 0.f ? 1.f / l : 0.f;
        int row = q0A + w * 16 + quad * 4 + r;
        size_t ob = ((size_t)b * 2048 + row) * 1024 + h * 64;
        for (int n = 0; n < 4; n++)
            out[ob + n * 16 + l15] = f2bf(OA[n][r] * inv);
    }
    for (int r = 0; r < 4; r++) {
        float l = lsB[r];
        l += __shfl_xor(l, 1, 64); l += __shfl_xor(l, 2, 64);
        l += __shfl_xor(l, 4, 64); l += __shfl_xor(l, 8, 64);
        float inv = l > 0.f ? 1.f / l : 0.f;
        int row = q0B + w * 16 + quad * 4 + r;
        size_t ob = ((size_t)b * 2048 + row) * 1024 + h * 64;
        for (int n = 0; n < 4; n++)
            out[ob + n * 16 + l15] = f2bf(OB[n][r] * inv);
    }
}

extern "C" void kernel_launch(void* const* d_in, const int* in_sizes, int n_in,
                              void* d_out, int out_size, void* d_ws, size_t ws_size,
                              hipStream_t stream) {
    const float* x = (const float*)d_in[0];
    const int* pad = (const int*)d_in[1];
    const int* cs = (const int*)d_in[2];
    const float* wqkv = (const float*)d_in[3];
    const float* wproj = (const float*)d_in[4];
    const float* bproj = (const float*)d_in[5];
    float* out = (float*)d_out;

    // ws (peak 32 MB): q[0,4M) k[4,8M) v[8,12M) ushorts;
    // wqkvT[12M,15M) dies after gemm1; ao[12M,16M); wprojT[0,1M) after q dies.
    // xbf lives in d_out (16 MB fp32 out >= 8 MB bf16 x) until gemm2 overwrites it.
    ushort_t* ws = (ushort_t*)d_ws;
    ushort_t* qws = ws;
    ushort_t* kws = ws + (size_t)4194304;
    ushort_t* vws = ws + (size_t)8388608;
    ushort_t* wqkvT = ws + (size_t)12582912;
    ushort_t* aows = ws + (size_t)12582912;
    ushort_t* wprojT = ws;
    ushort_t* xbf = (ushort_t*)d_out;

    transpose_f32_bf16<<<dim3(48, 16), 256, 0, stream>>>(wqkv, wqkvT, 1024, 3072);
    convert_f32_bf16<<<2048, 256, 0, stream>>>(x, xbf);
    gemm_bt<0><<<dim3(24, 32), 256, 0, stream>>>(xbf, wqkvT, 4096, 3072, 1024,
                                                 qws, kws, vws, nullptr, nullptr);
    attn_kernel<<<dim3(16, 32), 256, 0, stream>>>(qws, kws, vws, pad, cs, aows);
    transpose_f32_bf16<<<dim3(16, 16), 256, 0, stream>>>(wproj, wprojT, 1024, 1024);
    gemm_bt<1><<<dim3(8, 32), 256, 0, stream>>>(aows, wprojT, 4096, 1024, 1024,
                                                nullptr, nullptr, nullptr, bproj, out);
}